// Round 16
// baseline (162.409 us; speedup 1.0000x reference)
//
#include <hip/hip_runtime.h>
#include <hip/hip_bf16.h>

#define N_ELEM 1000000
#define D 128
#define S_SEG 65536
#define SEGW 8            // segments per wave: NBLK*4 waves * SEGW == S_SEG
#define NBLK 2048
#define NEG_BIG (-1e30f)

// DPP-based add of a shifted copy (pure VALU, no DS pipe).
#define DPP_ADD(v, CTRL) \
    v += __int_as_float(__builtin_amdgcn_update_dpp(0, __float_as_int(v), CTRL, 0xF, 0xF, true))

// Full 64-lane sum via DPP: row_shr 1/2/4/8 + row_bcast15 + row_bcast31,
// then readlane(63) -> SGPR (broadcast free to all lanes).
__device__ __forceinline__ float reduce64(float v) {
    DPP_ADD(v, 0x111);   // row_shr:1
    DPP_ADD(v, 0x112);   // row_shr:2
    DPP_ADD(v, 0x114);   // row_shr:4
    DPP_ADD(v, 0x118);   // row_shr:8
    DPP_ADD(v, 0x142);   // row_bcast:15
    DPP_ADD(v, 0x143);   // row_bcast:31
    return __int_as_float(__builtin_amdgcn_readlane(__float_as_int(v), 63));
}

// Online-softmax step on a float2-per-lane accumulator (row always valid).
__device__ __forceinline__ void osm2(float& m, float& l, float2& a,
                                     float d, float2 v) {
    float mn = fmaxf(m, d);
    float sc = __expf(m - mn);
    float p  = __expf(d - mn);
    m = mn;
    l = fmaf(l, sc, p);
    a.x = fmaf(a.x, sc, p * v.x);
    a.y = fmaf(a.y, sc, p * v.y);
}

// K1: continuous-stream kernel (round-14 known-good, 161.4 us total).
// One row per wave-load (float2/lane = 512B); the wave's SEGW segments form
// ONE sequential row range, consumed with an 8-deep register prefetch that
// never drains; segment boundaries are wave-uniform branches that
// finalize+reset state between consumes while prefetched loads stay in
// flight. emb reads HBM exactly once; no atomics; no zero-init.
__global__ __launch_bounds__(256, 6) void k_fused(
        const float* __restrict__ emb, const int* __restrict__ seg,
        const float* __restrict__ watt, float* __restrict__ out) {
    const int lane = threadIdx.x & 63;
    const int wid  = blockIdx.x * 4 + (threadIdx.x >> 6);
    const float2 wv = reinterpret_cast<const float2*>(watt)[lane];
    const float2* emb2 = reinterpret_cast<const float2*>(emb);
    float2* out2 = reinterpret_cast<float2*>(out);

    const int s0 = wid * SEGW;
    // lane i (i<=SEGW) holds lower_bound(seg, s0+i)
    int lo = 0;
    if (lane <= SEGW) {
        int target = s0 + lane, hi = N_ELEM;
        while (lo < hi) {
            int mid = (lo + hi) >> 1;
            if (seg[mid] < target) lo = mid + 1; else hi = mid;
        }
    }

    int si = 0;
    int e      = __shfl(lo, 0, 64);      // row cursor (wave-uniform)
    int endCur = __shfl(lo, 1, 64);      // end of current segment

    float mA = NEG_BIG, lA = 0.f; float2 aA = {0.f, 0.f};
    float mB = NEG_BIG, lB = 0.f; float2 aB = {0.f, 0.f};

    // prologue: prefetch rows e..e+7 (clamped)
    float2 r0 = emb2[(size_t)min(e + 0, N_ELEM - 1) * 64 + lane];
    float2 r1 = emb2[(size_t)min(e + 1, N_ELEM - 1) * 64 + lane];
    float2 r2 = emb2[(size_t)min(e + 2, N_ELEM - 1) * 64 + lane];
    float2 r3 = emb2[(size_t)min(e + 3, N_ELEM - 1) * 64 + lane];
    float2 r4 = emb2[(size_t)min(e + 4, N_ELEM - 1) * 64 + lane];
    float2 r5 = emb2[(size_t)min(e + 5, N_ELEM - 1) * 64 + lane];
    float2 r6 = emb2[(size_t)min(e + 6, N_ELEM - 1) * 64 + lane];
    float2 r7 = emb2[(size_t)min(e + 7, N_ELEM - 1) * 64 + lane];
    int p = e + 8;

#define FIN() do {                                                        \
        float mm = fmaxf(mA, mB);                                         \
        float w1 = __expf(mA - mm), w2 = __expf(mB - mm);                 \
        float ll = lA * w1 + lB * w2;                                     \
        float inv = (ll > 0.f) ? 1.0f / ll : 0.f;                         \
        float2 r;                                                         \
        r.x = (aA.x * w1 + aB.x * w2) * inv;                              \
        r.y = (aA.y * w1 + aB.y * w2) * inv;                              \
        out2[(size_t)(s0 + si) * 64 + lane] = r;                          \
        mA = mB = NEG_BIG; lA = lB = 0.f;                                 \
        aA.x = aA.y = aB.x = aB.y = 0.f;                                  \
        ++si;                                                             \
        if (si < SEGW) endCur = __shfl(lo, si + 1, 64);                   \
    } while (0)

#define SLOT(R, MS, LS, AS) do {                                          \
        while (si < SEGW && e == endCur) FIN();                           \
        if (si < SEGW) {                                                  \
            float d = reduce64(fmaf(R.x, wv.x, R.y * wv.y));              \
            osm2(MS, LS, AS, d, R);                                       \
            ++e;                                                          \
        }                                                                 \
    } while (0)

    #pragma unroll 1
    while (si < SEGW) {
        // issue next 8 sequential row loads (addresses independent of
        // segmentation -> pipeline never drains at boundaries)
        float2 n0 = emb2[(size_t)min(p + 0, N_ELEM - 1) * 64 + lane];
        float2 n1 = emb2[(size_t)min(p + 1, N_ELEM - 1) * 64 + lane];
        float2 n2 = emb2[(size_t)min(p + 2, N_ELEM - 1) * 64 + lane];
        float2 n3 = emb2[(size_t)min(p + 3, N_ELEM - 1) * 64 + lane];
        float2 n4 = emb2[(size_t)min(p + 4, N_ELEM - 1) * 64 + lane];
        float2 n5 = emb2[(size_t)min(p + 5, N_ELEM - 1) * 64 + lane];
        float2 n6 = emb2[(size_t)min(p + 6, N_ELEM - 1) * 64 + lane];
        float2 n7 = emb2[(size_t)min(p + 7, N_ELEM - 1) * 64 + lane];
        p += 8;
        SLOT(r0, mA, lA, aA);
        SLOT(r1, mB, lB, aB);
        SLOT(r2, mA, lA, aA);
        SLOT(r3, mB, lB, aB);
        SLOT(r4, mA, lA, aA);
        SLOT(r5, mB, lB, aB);
        SLOT(r6, mA, lA, aA);
        SLOT(r7, mB, lB, aB);
        r0 = n0; r1 = n1; r2 = n2; r3 = n3;
        r4 = n4; r5 = n5; r6 = n6; r7 = n7;
    }
#undef SLOT
#undef FIN
}

// K2: k-tiled in-place GEMM (round-11 version: 33.8 KB LDS -> 4 blocks/CU).
#define KT 32
#define PADR 132
__global__ __launch_bounds__(256, 4) void k_proj(
        float* __restrict__ out, const float* __restrict__ wout) {
    __shared__ float As[KT][PADR];   // As[kk][r] = out[r0+r][kt*32+kk]
    __shared__ float Bs[KT][PADR];   // Bs[kk][j] = wout[j][kt*32+kk]
    const int tid = threadIdx.x;
    const int r0 = blockIdx.x * 128;
    const int tx = tid & 15, ty = tid >> 4;
    const int rr = ty * 8, cc = tx * 8;
    float acc[8][8] = {};

    for (int kt = 0; kt < D / KT; ++kt) {
        #pragma unroll
        for (int i = 0; i < 4; ++i) {
            int idx = tid + i * 256;           // 0..1023
            int r = idx >> 3, k4 = idx & 7;    // row, float4-chunk in k-tile
            float4 a = *reinterpret_cast<const float4*>(
                &out[(size_t)(r0 + r) * D + kt * KT + k4 * 4]);
            float4 b = *reinterpret_cast<const float4*>(
                &wout[(size_t)r * D + kt * KT + k4 * 4]);
            As[k4 * 4 + 0][r] = a.x; As[k4 * 4 + 1][r] = a.y;
            As[k4 * 4 + 2][r] = a.z; As[k4 * 4 + 3][r] = a.w;
            Bs[k4 * 4 + 0][r] = b.x; Bs[k4 * 4 + 1][r] = b.y;
            Bs[k4 * 4 + 2][r] = b.z; Bs[k4 * 4 + 3][r] = b.w;
        }
        __syncthreads();
        #pragma unroll
        for (int kk = 0; kk < KT; ++kk) {
            float a[8], b[8];
            *reinterpret_cast<float4*>(&a[0]) = *reinterpret_cast<const float4*>(&As[kk][rr]);
            *reinterpret_cast<float4*>(&a[4]) = *reinterpret_cast<const float4*>(&As[kk][rr + 4]);
            *reinterpret_cast<float4*>(&b[0]) = *reinterpret_cast<const float4*>(&Bs[kk][cc]);
            *reinterpret_cast<float4*>(&b[4]) = *reinterpret_cast<const float4*>(&Bs[kk][cc + 4]);
            #pragma unroll
            for (int i = 0; i < 8; ++i)
                #pragma unroll
                for (int j = 0; j < 8; ++j)
                    acc[i][j] = fmaf(a[i], b[j], acc[i][j]);
        }
        __syncthreads();
    }
    #pragma unroll
    for (int i = 0; i < 8; ++i) {
        float4 o0 = {acc[i][0], acc[i][1], acc[i][2], acc[i][3]};
        float4 o1 = {acc[i][4], acc[i][5], acc[i][6], acc[i][7]};
        *reinterpret_cast<float4*>(&out[(size_t)(r0 + rr + i) * D + cc])     = o0;
        *reinterpret_cast<float4*>(&out[(size_t)(r0 + rr + i) * D + cc + 4]) = o1;
    }
}

extern "C" void kernel_launch(void* const* d_in, const int* in_sizes, int n_in,
                              void* d_out, int out_size, void* d_ws, size_t ws_size,
                              hipStream_t stream) {
    const float* emb  = (const float*)d_in[0];
    const int*   seg  = (const int*)d_in[1];
    const float* watt = (const float*)d_in[3];
    const float* wout = (const float*)d_in[4];
    float* out = (float*)d_out;

    k_fused<<<NBLK, 256, 0, stream>>>(emb, seg, watt, out);
    k_proj <<<S_SEG / 128, 256, 0, stream>>>(out, wout);
}

// Round 17
// 159.773 us; speedup vs baseline: 1.0165x; 1.0165x over previous
//
#include <hip/hip_runtime.h>
#include <hip/hip_bf16.h>

#define N_ELEM 1000000
#define D 128
#define S_SEG 65536
#define SEGW 8            // segments per wave: NBLK*4 waves * SEGW == S_SEG
#define NBLK 2048
#define NEG_BIG (-1e30f)

// DPP-based add of a shifted copy (pure VALU, no DS pipe).
#define DPP_ADD(v, CTRL) \
    v += __int_as_float(__builtin_amdgcn_update_dpp(0, __float_as_int(v), CTRL, 0xF, 0xF, true))

// Full 64-lane sum via DPP: row_shr 1/2/4/8 + row_bcast15 + row_bcast31,
// then readlane(63) -> SGPR (broadcast free to all lanes).
__device__ __forceinline__ float reduce64(float v) {
    DPP_ADD(v, 0x111);   // row_shr:1
    DPP_ADD(v, 0x112);   // row_shr:2
    DPP_ADD(v, 0x114);   // row_shr:4
    DPP_ADD(v, 0x118);   // row_shr:8
    DPP_ADD(v, 0x142);   // row_bcast:15
    DPP_ADD(v, 0x143);   // row_bcast:31
    return __int_as_float(__builtin_amdgcn_readlane(__float_as_int(v), 63));
}

// Online-softmax step on a float2-per-lane accumulator (row always valid).
__device__ __forceinline__ void osm2(float& m, float& l, float2& a,
                                     float d, float2 v) {
    float mn = fmaxf(m, d);
    float sc = __expf(m - mn);
    float p  = __expf(d - mn);
    m = mn;
    l = fmaf(l, sc, p);
    a.x = fmaf(a.x, sc, p * v.x);
    a.y = fmaf(a.y, sc, p * v.y);
}

// K1 (round-17): DRAIN-FREE ping-pong pipeline. Round-14's register rotation
// (r0=n0;...;r7=n7) forced vmcnt(0) every iteration -- the prefetch queue
// drained to zero outstanding once per iteration, exposing full loaded
// latency each time (and explaining why depth 4 vs 8 made no difference).
// Now: two 8-row register banks, unrolled x2 body {issue B; consume A;
// issue A; consume B} with NO copies -> the compiler can use counted
// vmcnt(15..8) waits and 8 loads stay in flight at all times.
// Same math/order as round 14 otherwise. emb reads HBM exactly once.
__global__ __launch_bounds__(256, 6) void k_fused(
        const float* __restrict__ emb, const int* __restrict__ seg,
        const float* __restrict__ watt, float* __restrict__ out) {
    const int lane = threadIdx.x & 63;
    const int wid  = blockIdx.x * 4 + (threadIdx.x >> 6);
    const float2 wv = reinterpret_cast<const float2*>(watt)[lane];
    const float2* emb2 = reinterpret_cast<const float2*>(emb);
    float2* out2 = reinterpret_cast<float2*>(out);

    const int s0 = wid * SEGW;
    // lane i (i<=SEGW) holds lower_bound(seg, s0+i)
    int lo = 0;
    if (lane <= SEGW) {
        int target = s0 + lane, hi = N_ELEM;
        while (lo < hi) {
            int mid = (lo + hi) >> 1;
            if (seg[mid] < target) lo = mid + 1; else hi = mid;
        }
    }

    int si = 0;
    int e      = __shfl(lo, 0, 64);      // row cursor (wave-uniform)
    int endCur = __shfl(lo, 1, 64);      // end of current segment

    float mA = NEG_BIG, lA = 0.f; float2 aA = {0.f, 0.f};
    float mB = NEG_BIG, lB = 0.f; float2 aB = {0.f, 0.f};

    // prologue: bank a = rows e..e+7 (clamped)
    float2 a0 = emb2[(size_t)min(e + 0, N_ELEM - 1) * 64 + lane];
    float2 a1 = emb2[(size_t)min(e + 1, N_ELEM - 1) * 64 + lane];
    float2 a2 = emb2[(size_t)min(e + 2, N_ELEM - 1) * 64 + lane];
    float2 a3 = emb2[(size_t)min(e + 3, N_ELEM - 1) * 64 + lane];
    float2 a4 = emb2[(size_t)min(e + 4, N_ELEM - 1) * 64 + lane];
    float2 a5 = emb2[(size_t)min(e + 5, N_ELEM - 1) * 64 + lane];
    float2 a6 = emb2[(size_t)min(e + 6, N_ELEM - 1) * 64 + lane];
    float2 a7 = emb2[(size_t)min(e + 7, N_ELEM - 1) * 64 + lane];
    int p = e + 8;

#define FIN() do {                                                        \
        float mm = fmaxf(mA, mB);                                         \
        float w1 = __expf(mA - mm), w2 = __expf(mB - mm);                 \
        float ll = lA * w1 + lB * w2;                                     \
        float inv = (ll > 0.f) ? 1.0f / ll : 0.f;                         \
        float2 r;                                                         \
        r.x = (aA.x * w1 + aB.x * w2) * inv;                              \
        r.y = (aA.y * w1 + aB.y * w2) * inv;                              \
        out2[(size_t)(s0 + si) * 64 + lane] = r;                          \
        mA = mB = NEG_BIG; lA = lB = 0.f;                                 \
        aA.x = aA.y = aB.x = aB.y = 0.f;                                  \
        ++si;                                                             \
        if (si < SEGW) endCur = __shfl(lo, si + 1, 64);                   \
    } while (0)

#define SLOT(R, MS, LS, AS) do {                                          \
        while (si < SEGW && e == endCur) FIN();                           \
        if (si < SEGW) {                                                  \
            float d = reduce64(fmaf(R.x, wv.x, R.y * wv.y));              \
            osm2(MS, LS, AS, d, R);                                       \
            ++e;                                                          \
        }                                                                 \
    } while (0)

    #pragma unroll 1
    while (si < SEGW) {
        // issue bank b (8 sequential rows) -- a-bank loads stay untouched
        float2 b0 = emb2[(size_t)min(p + 0, N_ELEM - 1) * 64 + lane];
        float2 b1 = emb2[(size_t)min(p + 1, N_ELEM - 1) * 64 + lane];
        float2 b2 = emb2[(size_t)min(p + 2, N_ELEM - 1) * 64 + lane];
        float2 b3 = emb2[(size_t)min(p + 3, N_ELEM - 1) * 64 + lane];
        float2 b4 = emb2[(size_t)min(p + 4, N_ELEM - 1) * 64 + lane];
        float2 b5 = emb2[(size_t)min(p + 5, N_ELEM - 1) * 64 + lane];
        float2 b6 = emb2[(size_t)min(p + 6, N_ELEM - 1) * 64 + lane];
        float2 b7 = emb2[(size_t)min(p + 7, N_ELEM - 1) * 64 + lane];
        p += 8;
        // consume bank a (waits only on a-loads: vmcnt keeps b in flight)
        SLOT(a0, mA, lA, aA);
        SLOT(a1, mB, lB, aB);
        SLOT(a2, mA, lA, aA);
        SLOT(a3, mB, lB, aB);
        SLOT(a4, mA, lA, aA);
        SLOT(a5, mB, lB, aB);
        SLOT(a6, mA, lA, aA);
        SLOT(a7, mB, lB, aB);
        if (si >= SEGW) break;
        // issue bank a
        a0 = emb2[(size_t)min(p + 0, N_ELEM - 1) * 64 + lane];
        a1 = emb2[(size_t)min(p + 1, N_ELEM - 1) * 64 + lane];
        a2 = emb2[(size_t)min(p + 2, N_ELEM - 1) * 64 + lane];
        a3 = emb2[(size_t)min(p + 3, N_ELEM - 1) * 64 + lane];
        a4 = emb2[(size_t)min(p + 4, N_ELEM - 1) * 64 + lane];
        a5 = emb2[(size_t)min(p + 5, N_ELEM - 1) * 64 + lane];
        a6 = emb2[(size_t)min(p + 6, N_ELEM - 1) * 64 + lane];
        a7 = emb2[(size_t)min(p + 7, N_ELEM - 1) * 64 + lane];
        p += 8;
        // consume bank b
        SLOT(b0, mA, lA, aA);
        SLOT(b1, mB, lB, aB);
        SLOT(b2, mA, lA, aA);
        SLOT(b3, mB, lB, aB);
        SLOT(b4, mA, lA, aA);
        SLOT(b5, mB, lB, aB);
        SLOT(b6, mA, lA, aA);
        SLOT(b7, mB, lB, aB);
    }
#undef SLOT
#undef FIN
}

// K2: k-tiled in-place GEMM (round-11 version: 33.8 KB LDS -> 4 blocks/CU).
#define KT 32
#define PADR 132
__global__ __launch_bounds__(256, 4) void k_proj(
        float* __restrict__ out, const float* __restrict__ wout) {
    __shared__ float As[KT][PADR];   // As[kk][r] = out[r0+r][kt*32+kk]
    __shared__ float Bs[KT][PADR];   // Bs[kk][j] = wout[j][kt*32+kk]
    const int tid = threadIdx.x;
    const int r0 = blockIdx.x * 128;
    const int tx = tid & 15, ty = tid >> 4;
    const int rr = ty * 8, cc = tx * 8;
    float acc[8][8] = {};

    for (int kt = 0; kt < D / KT; ++kt) {
        #pragma unroll
        for (int i = 0; i < 4; ++i) {
            int idx = tid + i * 256;           // 0..1023
            int r = idx >> 3, k4 = idx & 7;    // row, float4-chunk in k-tile
            float4 a = *reinterpret_cast<const float4*>(
                &out[(size_t)(r0 + r) * D + kt * KT + k4 * 4]);
            float4 b = *reinterpret_cast<const float4*>(
                &wout[(size_t)r * D + kt * KT + k4 * 4]);
            As[k4 * 4 + 0][r] = a.x; As[k4 * 4 + 1][r] = a.y;
            As[k4 * 4 + 2][r] = a.z; As[k4 * 4 + 3][r] = a.w;
            Bs[k4 * 4 + 0][r] = b.x; Bs[k4 * 4 + 1][r] = b.y;
            Bs[k4 * 4 + 2][r] = b.z; Bs[k4 * 4 + 3][r] = b.w;
        }
        __syncthreads();
        #pragma unroll
        for (int kk = 0; kk < KT; ++kk) {
            float a[8], b[8];
            *reinterpret_cast<float4*>(&a[0]) = *reinterpret_cast<const float4*>(&As[kk][rr]);
            *reinterpret_cast<float4*>(&a[4]) = *reinterpret_cast<const float4*>(&As[kk][rr + 4]);
            *reinterpret_cast<float4*>(&b[0]) = *reinterpret_cast<const float4*>(&Bs[kk][cc]);
            *reinterpret_cast<float4*>(&b[4]) = *reinterpret_cast<const float4*>(&Bs[kk][cc + 4]);
            #pragma unroll
            for (int i = 0; i < 8; ++i)
                #pragma unroll
                for (int j = 0; j < 8; ++j)
                    acc[i][j] = fmaf(a[i], b[j], acc[i][j]);
        }
        __syncthreads();
    }
    #pragma unroll
    for (int i = 0; i < 8; ++i) {
        float4 o0 = {acc[i][0], acc[i][1], acc[i][2], acc[i][3]};
        float4 o1 = {acc[i][4], acc[i][5], acc[i][6], acc[i][7]};
        *reinterpret_cast<float4*>(&out[(size_t)(r0 + rr + i) * D + cc])     = o0;
        *reinterpret_cast<float4*>(&out[(size_t)(r0 + rr + i) * D + cc + 4]) = o1;
    }
}

extern "C" void kernel_launch(void* const* d_in, const int* in_sizes, int n_in,
                              void* d_out, int out_size, void* d_ws, size_t ws_size,
                              hipStream_t stream) {
    const float* emb  = (const float*)d_in[0];
    const int*   seg  = (const int*)d_in[1];
    const float* watt = (const float*)d_in[3];
    const float* wout = (const float*)d_in[4];
    float* out = (float*)d_out;

    k_fused<<<NBLK, 256, 0, stream>>>(emb, seg, watt, out);
    k_proj <<<S_SEG / 128, 256, 0, stream>>>(out, wout);
}